// Round 3
// baseline (1287.348 us; speedup 1.0000x reference)
//
#include <hip/hip_runtime.h>
#include <math.h>

#define D_ 128
#define H_ 160
#define W_ 160
#define NVOX (D_*H_*W_)
#define HW (H_*W_)

// Gaussian kernel, sigma=1, radius=2, normalized
#define K0 0.40261996f
#define K1 0.24420134f
#define K2 0.05448868f

__device__ __forceinline__ float fetch_mov(const float* __restrict__ m, int d, int h, int w) {
    if ((unsigned)d >= (unsigned)D_ || (unsigned)h >= (unsigned)H_ || (unsigned)w >= (unsigned)W_) return 0.0f;
    return m[(size_t)(d*H_ + h)*W_ + w];
}

// gradient of fixed image: jnp.gradient semantics (central interior, one-sided edges)
__global__ void grad_kernel(const float* __restrict__ f, float* __restrict__ g) {
    int i = blockIdx.x*blockDim.x + threadIdx.x;
    if (i >= NVOX) return;
    int w = i % W_;
    int h = (i / W_) % H_;
    int d = i / HW;
    float gd, gh, gw;
    if (d == 0)            gd = f[i + HW] - f[i];
    else if (d == D_-1)    gd = f[i] - f[i - HW];
    else                   gd = 0.5f*(f[i + HW] - f[i - HW]);
    if (h == 0)            gh = f[i + W_] - f[i];
    else if (h == H_-1)    gh = f[i] - f[i - W_];
    else                   gh = 0.5f*(f[i + W_] - f[i - W_]);
    if (w == 0)            gw = f[i + 1] - f[i];
    else if (w == W_-1)    gw = f[i] - f[i - 1];
    else                   gw = 0.5f*(f[i + 1] - f[i - 1]);
    g[i]         = gd;
    g[NVOX + i]  = gh;
    g[2*NVOX + i]= gw;
}

// ---------------------------------------------------------------------------
// Fused warp + demons force. Block tiles 16x16 in (H,W); streams D through a
// 3-plane LDS ring of warped values (1-voxel halo in H,W). Force (gradient of
// warped + demons update) computed from the ring. vf_out must differ from
// vf_in (halo reads race with in-place writes otherwise).
// Grid: (W_/16, H_/16, D_/FC), block (16,16).
// ---------------------------------------------------------------------------
#define FC 8

__global__ __launch_bounds__(256) void warp_force_kernel(const float* __restrict__ mov,
                                                         const float* __restrict__ fix,
                                                         const float* __restrict__ gfix,
                                                         const float* __restrict__ vf_in,
                                                         float* __restrict__ vf_out) {
    __shared__ float wp[3][18][18];
    const int tx = threadIdx.x;        // W
    const int ty = threadIdx.y;        // H
    const int tid = ty*16 + tx;
    const int w0 = blockIdx.x * 16;
    const int h0 = blockIdx.y * 16;
    const int d0 = blockIdx.z * FC;

    for (int dd = d0-1; dd <= d0+FC; ++dd) {
        int slot = (dd + 3) % 3;
        if ((unsigned)dd < (unsigned)D_) {
            for (int idx = tid; idx < 324; idx += 256) {
                int lh = idx / 18, lw = idx % 18;
                int gh = h0 - 1 + lh, gw = w0 - 1 + lw;
                float val = 0.0f;
                if ((unsigned)gh < (unsigned)H_ && (unsigned)gw < (unsigned)W_) {
                    size_t base = (size_t)dd*HW + gh*W_ + gw;
                    float cd = (float)dd + vf_in[base];
                    float ch = (float)gh + vf_in[NVOX + base];
                    float cw = (float)gw + vf_in[2*NVOX + base];
                    float fd = floorf(cd), fh = floorf(ch), fw = floorf(cw);
                    int di = (int)fd, hi = (int)fh, wi = (int)fw;
                    float td = cd - fd, th = ch - fh, tw = cw - fw;
                    float c000, c001, c010, c011, c100, c101, c110, c111;
                    if (di >= 0 && di < D_-1 && hi >= 0 && hi < H_-1 && wi >= 0 && wi < W_-1) {
                        const float* p = mov + (size_t)di*HW + hi*W_ + wi;
                        c000 = p[0];    c001 = p[1];
                        c010 = p[W_];   c011 = p[W_+1];
                        const float* q = p + HW;
                        c100 = q[0];    c101 = q[1];
                        c110 = q[W_];   c111 = q[W_+1];
                    } else {
                        c000 = fetch_mov(mov, di,   hi,   wi  );
                        c001 = fetch_mov(mov, di,   hi,   wi+1);
                        c010 = fetch_mov(mov, di,   hi+1, wi  );
                        c011 = fetch_mov(mov, di,   hi+1, wi+1);
                        c100 = fetch_mov(mov, di+1, hi,   wi  );
                        c101 = fetch_mov(mov, di+1, hi,   wi+1);
                        c110 = fetch_mov(mov, di+1, hi+1, wi  );
                        c111 = fetch_mov(mov, di+1, hi+1, wi+1);
                    }
                    float c00 = c000 + tw*(c001 - c000);
                    float c01 = c010 + tw*(c011 - c010);
                    float c10 = c100 + tw*(c101 - c100);
                    float c11 = c110 + tw*(c111 - c110);
                    float c0 = c00 + th*(c01 - c00);
                    float c1 = c10 + th*(c11 - c10);
                    val = c0 + td*(c1 - c0);
                }
                wp[slot][lh][lw] = val;
            }
        } else {
            for (int idx = tid; idx < 324; idx += 256) wp[slot][idx/18][idx%18] = 0.0f;
        }
        __syncthreads();
        int pd = dd - 1;
        if (pd >= d0 && pd < d0 + FC) {
            int sc = (pd + 3) % 3;       // center plane slot
            int sm = (pd + 2) % 3;       // pd-1
            int sp = (pd + 4) % 3;       // pd+1
            int lh = ty + 1, lw = tx + 1;
            float wc = wp[sc][lh][lw];
            float gd;
            if (pd == 0)            gd = wp[sp][lh][lw] - wc;
            else if (pd == D_-1)    gd = wc - wp[sm][lh][lw];
            else                    gd = 0.5f*(wp[sp][lh][lw] - wp[sm][lh][lw]);
            int ghp = h0 + ty;
            float ghv;
            if (ghp == 0)           ghv = wp[sc][lh+1][lw] - wc;
            else if (ghp == H_-1)   ghv = wc - wp[sc][lh-1][lw];
            else                    ghv = 0.5f*(wp[sc][lh+1][lw] - wp[sc][lh-1][lw]);
            int gwp = w0 + tx;
            float gwv;
            if (gwp == 0)           gwv = wp[sc][lh][lw+1] - wc;
            else if (gwp == W_-1)   gwv = wc - wp[sc][lh][lw-1];
            else                    gwv = 0.5f*(wp[sc][lh][lw+1] - wp[sc][lh][lw-1]);
            size_t i = (size_t)pd*HW + ghp*W_ + gwp;
            float diff = wc - fix[i];
            float g0 = gd  + gfix[i];
            float g1 = ghv + gfix[NVOX + i];
            float g2 = gwv + gfix[2*NVOX + i];
            float denom = g0*g0 + g1*g1 + g2*g2 + diff*diff;
            float scale = (denom > 1e-6f) ? (-diff/denom) : 0.0f;
            vf_out[i]          = vf_in[i]          + scale*g0;
            vf_out[NVOX + i]   = vf_in[NVOX + i]   + scale*g1;
            vf_out[2*NVOX + i] = vf_in[2*NVOX + i] + scale*g2;
        }
        __syncthreads();   // ring slot (dd+1)%3 is overwritten next iteration
    }
}

// ---------------------------------------------------------------------------
// Fused separable 3D Gaussian. 32x32 (H,W) tile, block (32,16) = 512 threads
// (each thread owns 2 H-rows). D streamed with 5-deep register windows.
// Next-plane loads prefetched into registers before the barriers.
// Grid: (W_/32, H_/32, (D_/SCHUNK)*3), block (32,16).
// ---------------------------------------------------------------------------
#define SCHUNK 8

__global__ __launch_bounds__(512) void smooth3d_kernel(const float* __restrict__ src,
                                                       float* __restrict__ dst) {
    __shared__ float raw[36][36];
    __shared__ float s1[36][32];
    const int tx = threadIdx.x;     // 0..31 (W)
    const int ty = threadIdx.y;     // 0..15 (H pair)
    const int tid = ty*32 + tx;
    const int w0 = blockIdx.x * 32;
    const int h0 = blockIdx.y * 32;
    const int nchunk = D_ / SCHUNK;
    const int c  = blockIdx.z / nchunk;
    const int d0 = (blockIdx.z % nchunk) * SCHUNK;
    const float* s = src + (size_t)c * NVOX;
    float*       o = dst + (size_t)c * NVOX;

    // staging geometry (independent of plane)
    const int i1 = tid + 512, i2 = tid + 1024;
    const int lh0 = tid/36, lw0 = tid%36;
    const int lh1 = i1/36,  lw1 = i1%36;
    const int lh2 = i2/36,  lw2 = i2%36;
    const int gh0 = h0-2+lh0, gw0 = w0-2+lw0;
    const int gh1 = h0-2+lh1, gw1 = w0-2+lw1;
    const int gh2 = h0-2+lh2, gw2 = w0-2+lw2;
    const bool b0 = (unsigned)gh0 < (unsigned)H_ && (unsigned)gw0 < (unsigned)W_;
    const bool b1 = (unsigned)gh1 < (unsigned)H_ && (unsigned)gw1 < (unsigned)W_;
    const bool b2 = (i2 < 1296) && (unsigned)gh2 < (unsigned)H_ && (unsigned)gw2 < (unsigned)W_;
    const int o0 = gh0*W_+gw0, o1 = gh1*W_+gw1, o2 = gh2*W_+gw2;

    float wa0=0.f,wa1=0.f,wa2=0.f,wa3=0.f,wa4=0.f;
    float wb0=0.f,wb1=0.f,wb2=0.f,wb3=0.f,wb4=0.f;

    float p0=0.f, p1=0.f, p2=0.f;
    {
        int dd = d0-2;
        if ((unsigned)dd < (unsigned)D_) {
            const float* sp = s + (size_t)dd*HW;
            p0 = b0 ? sp[o0] : 0.0f;
            p1 = b1 ? sp[o1] : 0.0f;
            p2 = b2 ? sp[o2] : 0.0f;
        }
    }

    for (int dd = d0-2; dd < d0+SCHUNK+2; ++dd) {
        raw[lh0][lw0] = p0;
        raw[lh1][lw1] = p1;
        if (i2 < 1296) raw[lh2][lw2] = p2;
        // prefetch next plane into registers (latency overlaps barriers+conv)
        p0 = p1 = p2 = 0.0f;
        int dn = dd + 1;
        if (dn < d0+SCHUNK+2 && (unsigned)dn < (unsigned)D_) {
            const float* sp = s + (size_t)dn*HW;
            p0 = b0 ? sp[o0] : 0.0f;
            p1 = b1 ? sp[o1] : 0.0f;
            p2 = b2 ? sp[o2] : 0.0f;
        }
        __syncthreads();
        // W-conv: 36 rows
        {
            int r = ty;
            s1[r][tx] = K2*(raw[r][tx]+raw[r][tx+4]) + K1*(raw[r][tx+1]+raw[r][tx+3]) + K0*raw[r][tx+2];
            r = ty + 16;
            s1[r][tx] = K2*(raw[r][tx]+raw[r][tx+4]) + K1*(raw[r][tx+1]+raw[r][tx+3]) + K0*raw[r][tx+2];
            if (ty < 4) {
                r = ty + 32;
                s1[r][tx] = K2*(raw[r][tx]+raw[r][tx+4]) + K1*(raw[r][tx+1]+raw[r][tx+3]) + K0*raw[r][tx+2];
            }
        }
        __syncthreads();
        // H-conv for the two owned rows
        float s2a = K2*(s1[ty   ][tx]+s1[ty+ 4][tx]) + K1*(s1[ty+ 1][tx]+s1[ty+ 3][tx]) + K0*s1[ty+ 2][tx];
        float s2b = K2*(s1[ty+16][tx]+s1[ty+20][tx]) + K1*(s1[ty+17][tx]+s1[ty+19][tx]) + K0*s1[ty+18][tx];
        // D rolling windows
        wa0=wa1; wa1=wa2; wa2=wa3; wa3=wa4; wa4=s2a;
        wb0=wb1; wb1=wb2; wb2=wb3; wb3=wb4; wb4=s2b;
        int od = dd - 2;
        if (od >= d0) {
            float va = K2*(wa0+wa4) + K1*(wa1+wa3) + K0*wa2;
            float vb = K2*(wb0+wb4) + K1*(wb1+wb3) + K0*wb2;
            o[(size_t)od*HW + (h0+ty   )*W_ + w0+tx] = va;
            o[(size_t)od*HW + (h0+ty+16)*W_ + w0+tx] = vb;
        }
    }
}

extern "C" void kernel_launch(void* const* d_in, const int* in_sizes, int n_in,
                              void* d_out, int out_size, void* d_ws, size_t ws_size,
                              hipStream_t stream) {
    const float* mov = (const float*)d_in[0];
    const float* fix = (const float*)d_in[1];
    const int ITERS = 10;

    float* ws   = (float*)d_ws;
    float* gfix = ws;               // 3N
    float* vfA  = ws + (size_t)3*NVOX;  // 3N
    // If ws is large enough, keep the warp_force output in ws and let the
    // final smooth write d_out directly (saves the trailing D2D copy).
    bool big = ws_size >= (size_t)9*NVOX*sizeof(float);
    float* vfB = big ? (ws + (size_t)6*NVOX) : (float*)d_out;

    const int nb1 = (NVOX + 255)/256;

    grad_kernel<<<nb1, 256, 0, stream>>>(fix, gfix);
    hipMemsetAsync(vfA, 0, (size_t)3*NVOX*sizeof(float), stream);

    dim3 fg(W_/16, H_/16, D_/FC);
    dim3 fb(16, 16);
    dim3 sg(W_/32, H_/32, (D_/SCHUNK)*3);
    dim3 sb(32, 16);

    for (int it = 0; it < ITERS; ++it) {
        warp_force_kernel<<<fg, fb, 0, stream>>>(mov, fix, gfix, vfA, vfB);
        float* sdst = (big && it == ITERS-1) ? (float*)d_out : vfA;
        smooth3d_kernel<<<sg, sb, 0, stream>>>(vfB, sdst);
    }
    if (!big) {
        hipMemcpyAsync(d_out, vfA, (size_t)3*NVOX*sizeof(float), hipMemcpyDeviceToDevice, stream);
    }
}

// Round 4
// 873.558 us; speedup vs baseline: 1.4737x; 1.4737x over previous
//
#include <hip/hip_runtime.h>
#include <math.h>

#define D_ 128
#define H_ 160
#define W_ 160
#define NVOX (D_*H_*W_)
#define HW (H_*W_)
#define N4 (NVOX/4)

// Gaussian kernel, sigma=1, radius=2, normalized
#define K0 0.40261996f
#define K1 0.24420134f
#define K2 0.05448868f

union F4 { float4 v; float a[4]; };

__device__ __forceinline__ float4 zero4() { float4 z; z.x=z.y=z.z=z.w=0.f; return z; }

__device__ __forceinline__ float fetch_mov(const float* __restrict__ m, int d, int h, int w) {
    if ((unsigned)d >= (unsigned)D_ || (unsigned)h >= (unsigned)H_ || (unsigned)w >= (unsigned)W_) return 0.0f;
    return m[(size_t)(d*H_ + h)*W_ + w];
}

// ---------------------------------------------------------------------------
// gradient of fixed image (jnp.gradient semantics), float4 per thread
// ---------------------------------------------------------------------------
__global__ __launch_bounds__(256) void grad_kernel(const float* __restrict__ f, float* __restrict__ g) {
    int i4 = blockIdx.x*blockDim.x + threadIdx.x;
    if (i4 >= N4) return;
    int base = 4*i4;
    int w = base % W_;
    int h = (base / W_) % H_;
    int d = base / HW;
    const float4* f4 = (const float4*)f;
    F4 c;  c.v  = f4[i4];
    float cl = (w > 0)     ? f[base-1] : 0.f;
    float cr = (w+4 < W_)  ? f[base+4] : 0.f;
    F4 hu; hu.v = (h < H_-1) ? f4[i4 + W_/4]  : c.v;
    F4 hd; hd.v = (h > 0)    ? f4[i4 - W_/4]  : c.v;
    F4 du; du.v = (d < D_-1) ? f4[i4 + HW/4]  : c.v;
    F4 dn; dn.v = (d > 0)    ? f4[i4 - HW/4]  : c.v;
    float hs = (h==0 || h==H_-1) ? 1.f : 0.5f;
    float dsc = (d==0 || d==D_-1) ? 1.f : 0.5f;
    float m[6] = {cl, c.a[0], c.a[1], c.a[2], c.a[3], cr};
    F4 gd, gh, gw;
    #pragma unroll
    for (int j = 0; j < 4; ++j) {
        int wj = w + j;
        float prev = (wj == 0)     ? m[1] : m[j];
        float next = (wj == W_-1)  ? m[4] : m[j+2];
        float wsc  = (wj == 0 || wj == W_-1) ? 1.f : 0.5f;
        gw.a[j] = wsc*(next - prev);
        gh.a[j] = hs*(hu.a[j] - hd.a[j]);
        gd.a[j] = dsc*(du.a[j] - dn.a[j]);
    }
    ((float4*)g)[i4]        = gd.v;
    ((float4*)g)[i4 + N4]   = gh.v;
    ((float4*)g)[i4 + 2*N4] = gw.v;
}

// ---------------------------------------------------------------------------
// trilinear warp, 4 voxels per thread (float4 vf reads, 32 independent gathers)
// ---------------------------------------------------------------------------
__global__ __launch_bounds__(256) void warp_kernel(const float* __restrict__ mov,
                                                   const float* __restrict__ vf,
                                                   float* __restrict__ out) {
    int i4 = blockIdx.x*blockDim.x + threadIdx.x;
    if (i4 >= N4) return;
    int base = 4*i4;
    int w = base % W_;
    int h = (base / W_) % H_;
    int d = base / HW;
    const float4* vf4 = (const float4*)vf;
    F4 u0; u0.v = vf4[i4];
    F4 u1; u1.v = vf4[i4 + N4];
    F4 u2; u2.v = vf4[i4 + 2*N4];
    F4 r;
    #pragma unroll
    for (int j = 0; j < 4; ++j) {
        float cd = (float)d     + u0.a[j];
        float ch = (float)h     + u1.a[j];
        float cw = (float)(w+j) + u2.a[j];
        float fd = floorf(cd), fh = floorf(ch), fw = floorf(cw);
        int di = (int)fd, hi = (int)fh, wi = (int)fw;
        float td = cd - fd, th = ch - fh, tw = cw - fw;
        float c000, c001, c010, c011, c100, c101, c110, c111;
        if (di >= 0 && di < D_-1 && hi >= 0 && hi < H_-1 && wi >= 0 && wi < W_-1) {
            const float* p = mov + (size_t)di*HW + hi*W_ + wi;
            c000 = p[0];    c001 = p[1];
            c010 = p[W_];   c011 = p[W_+1];
            const float* q = p + HW;
            c100 = q[0];    c101 = q[1];
            c110 = q[W_];   c111 = q[W_+1];
        } else {
            c000 = fetch_mov(mov, di,   hi,   wi  );
            c001 = fetch_mov(mov, di,   hi,   wi+1);
            c010 = fetch_mov(mov, di,   hi+1, wi  );
            c011 = fetch_mov(mov, di,   hi+1, wi+1);
            c100 = fetch_mov(mov, di+1, hi,   wi  );
            c101 = fetch_mov(mov, di+1, hi,   wi+1);
            c110 = fetch_mov(mov, di+1, hi+1, wi  );
            c111 = fetch_mov(mov, di+1, hi+1, wi+1);
        }
        float c00 = c000 + tw*(c001 - c000);
        float c01 = c010 + tw*(c011 - c010);
        float c10 = c100 + tw*(c101 - c100);
        float c11 = c110 + tw*(c111 - c110);
        float c0 = c00 + th*(c01 - c00);
        float c1 = c10 + th*(c11 - c10);
        r.a[j] = c0 + td*(c1 - c0);
    }
    ((float4*)out)[i4] = r.v;
}

// ---------------------------------------------------------------------------
// demon force + vf update (in-place), 4 voxels per thread
// ---------------------------------------------------------------------------
__global__ __launch_bounds__(256) void force_kernel(const float* __restrict__ warped,
                                                    const float* __restrict__ fix,
                                                    const float* __restrict__ gfix,
                                                    float* __restrict__ vf) {
    int i4 = blockIdx.x*blockDim.x + threadIdx.x;
    if (i4 >= N4) return;
    int base = 4*i4;
    int w = base % W_;
    int h = (base / W_) % H_;
    int d = base / HW;
    const float4* w4p = (const float4*)warped;
    F4 c;  c.v  = w4p[i4];
    float cl = (w > 0)     ? warped[base-1] : 0.f;
    float cr = (w+4 < W_)  ? warped[base+4] : 0.f;
    F4 hu; hu.v = (h < H_-1) ? w4p[i4 + W_/4] : c.v;
    F4 hd; hd.v = (h > 0)    ? w4p[i4 - W_/4] : c.v;
    F4 du; du.v = (d < D_-1) ? w4p[i4 + HW/4] : c.v;
    F4 dn; dn.v = (d > 0)    ? w4p[i4 - HW/4] : c.v;
    float hs  = (h==0 || h==H_-1) ? 1.f : 0.5f;
    float dsc = (d==0 || d==D_-1) ? 1.f : 0.5f;
    F4 fx; fx.v = ((const float4*)fix)[i4];
    F4 g0; g0.v = ((const float4*)gfix)[i4];
    F4 g1; g1.v = ((const float4*)gfix)[i4 + N4];
    F4 g2; g2.v = ((const float4*)gfix)[i4 + 2*N4];
    float4* vf4 = (float4*)vf;
    F4 v0; v0.v = vf4[i4];
    F4 v1; v1.v = vf4[i4 + N4];
    F4 v2; v2.v = vf4[i4 + 2*N4];
    float m[6] = {cl, c.a[0], c.a[1], c.a[2], c.a[3], cr};
    #pragma unroll
    for (int j = 0; j < 4; ++j) {
        int wj = w + j;
        float prev = (wj == 0)    ? m[1] : m[j];
        float next = (wj == W_-1) ? m[4] : m[j+2];
        float wsc  = (wj == 0 || wj == W_-1) ? 1.f : 0.5f;
        float gwv = wsc*(next - prev);
        float ghv = hs*(hu.a[j] - hd.a[j]);
        float gdv = dsc*(du.a[j] - dn.a[j]);
        float diff = c.a[j] - fx.a[j];
        float G0 = gdv + g0.a[j];
        float G1 = ghv + g1.a[j];
        float G2 = gwv + g2.a[j];
        float denom = G0*G0 + G1*G1 + G2*G2 + diff*diff;
        float scale = (denom > 1e-6f) ? (-diff/denom) : 0.0f;
        v0.a[j] += scale*G0;
        v1.a[j] += scale*G1;
        v2.a[j] += scale*G2;
    }
    vf4[i4]        = v0.v;
    vf4[i4 + N4]   = v1.v;
    vf4[i4 + 2*N4] = v2.v;
}

// ---------------------------------------------------------------------------
// Fused separable 3D Gaussian, fully float4 on the global path.
// Block (8,32): 32x32 (W,H) tile, D streamed (SCHUNK planes out, +4 halo).
// raw: 36 rows x 40 cols (w0-4..w0+35, aligned float4); s1: W-conv result.
// Grid (5,5,16*3).
// ---------------------------------------------------------------------------
#define SCHUNK 8

__global__ __launch_bounds__(256) void smooth3d_kernel(const float* __restrict__ src,
                                                       float* __restrict__ dst) {
    __shared__ float raw[36][40];
    __shared__ float s1[36][36];   // cols 0..31 used; stride 36 keeps float4 alignment
    const int tx = threadIdx.x;    // 0..7
    const int ty = threadIdx.y;    // 0..31
    const int tid = ty*8 + tx;
    const int w0 = blockIdx.x * 32;
    const int h0 = blockIdx.y * 32;
    const int c  = blockIdx.z / (D_/SCHUNK);
    const int d0 = (blockIdx.z % (D_/SCHUNK)) * SCHUNK;
    const float* s = src + (size_t)c * NVOX;
    float*       o = dst + (size_t)c * NVOX;

    // staging geometry: 360 float4 slots (36 rows x 10 cols)
    const int idxB = tid + 256;
    const int rA = tid/10,  cA = tid%10;
    const int rB = idxB/10, cB = idxB%10;
    const int ghA = h0-2+rA, gwA = w0-4+4*cA;
    const int ghB = h0-2+rB, gwB = w0-4+4*cB;
    const bool hasB = (tid < 104);
    const bool bA = (unsigned)ghA < (unsigned)H_ && (unsigned)gwA < (unsigned)W_;
    const bool bB = hasB && (unsigned)ghB < (unsigned)H_ && (unsigned)gwB < (unsigned)W_;
    const int oA = ghA*W_ + gwA;
    const int oB = ghB*W_ + gwB;

    float4 wn0=zero4(), wn1=zero4(), wn2=zero4(), wn3=zero4(), wn4=zero4();

    float4 pA = zero4(), pB = zero4();
    {
        int dd = d0-2;
        if ((unsigned)dd < (unsigned)D_) {
            const float* sp = s + (size_t)dd*HW;
            if (bA) pA = *(const float4*)(sp + oA);
            if (bB) pB = *(const float4*)(sp + oB);
        }
    }

    for (int dd = d0-2; dd < d0+SCHUNK+2; ++dd) {
        *(float4*)&raw[rA][4*cA] = pA;
        if (hasB) *(float4*)&raw[rB][4*cB] = pB;
        // prefetch next plane (latency overlaps conv + barriers)
        pA = zero4(); pB = zero4();
        int dn2 = dd + 1;
        if (dn2 < d0+SCHUNK+2 && (unsigned)dn2 < (unsigned)D_) {
            const float* sp = s + (size_t)dn2*HW;
            if (bA) pA = *(const float4*)(sp + oA);
            if (bB) pB = *(const float4*)(sp + oB);
        }
        __syncthreads();
        // W-conv: rows ty and (ty<4) ty+32; outputs cols 4tx..4tx+3
        {
            int r = ty;
            const float4* rr = (const float4*)&raw[r][0];
            F4 a, b, cc;
            a.v = rr[tx]; b.v = rr[tx+1]; cc.v = rr[tx+2];
            float m[12];
            #pragma unroll
            for (int j=0;j<4;++j){ m[j]=a.a[j]; m[4+j]=b.a[j]; m[8+j]=cc.a[j]; }
            F4 out;
            #pragma unroll
            for (int j=0;j<4;++j)
                out.a[j] = K2*(m[j+2]+m[j+6]) + K1*(m[j+3]+m[j+5]) + K0*m[j+4];
            *(float4*)&s1[r][4*tx] = out.v;
            if (ty < 4) {
                r = ty + 32;
                rr = (const float4*)&raw[r][0];
                a.v = rr[tx]; b.v = rr[tx+1]; cc.v = rr[tx+2];
                #pragma unroll
                for (int j=0;j<4;++j){ m[j]=a.a[j]; m[4+j]=b.a[j]; m[8+j]=cc.a[j]; }
                #pragma unroll
                for (int j=0;j<4;++j)
                    out.a[j] = K2*(m[j+2]+m[j+6]) + K1*(m[j+3]+m[j+5]) + K0*m[j+4];
                *(float4*)&s1[r][4*tx] = out.v;
            }
        }
        __syncthreads();
        // H-conv (rows ty..ty+4) -> float4, then D rolling window
        float4 q0 = *(const float4*)&s1[ty  ][4*tx];
        float4 q1 = *(const float4*)&s1[ty+1][4*tx];
        float4 q2 = *(const float4*)&s1[ty+2][4*tx];
        float4 q3 = *(const float4*)&s1[ty+3][4*tx];
        float4 q4 = *(const float4*)&s1[ty+4][4*tx];
        float4 s2;
        s2.x = K2*(q0.x+q4.x) + K1*(q1.x+q3.x) + K0*q2.x;
        s2.y = K2*(q0.y+q4.y) + K1*(q1.y+q3.y) + K0*q2.y;
        s2.z = K2*(q0.z+q4.z) + K1*(q1.z+q3.z) + K0*q2.z;
        s2.w = K2*(q0.w+q4.w) + K1*(q1.w+q3.w) + K0*q2.w;
        wn0 = wn1; wn1 = wn2; wn2 = wn3; wn3 = wn4; wn4 = s2;
        int od = dd - 2;
        if (od >= d0) {
            float4 v;
            v.x = K2*(wn0.x+wn4.x) + K1*(wn1.x+wn3.x) + K0*wn2.x;
            v.y = K2*(wn0.y+wn4.y) + K1*(wn1.y+wn3.y) + K0*wn2.y;
            v.z = K2*(wn0.z+wn4.z) + K1*(wn1.z+wn3.z) + K0*wn2.z;
            v.w = K2*(wn0.w+wn4.w) + K1*(wn1.w+wn3.w) + K0*wn2.w;
            *(float4*)(o + (size_t)od*HW + (h0+ty)*W_ + w0 + 4*tx) = v;
        }
    }
}

extern "C" void kernel_launch(void* const* d_in, const int* in_sizes, int n_in,
                              void* d_out, int out_size, void* d_ws, size_t ws_size,
                              hipStream_t stream) {
    const float* mov = (const float*)d_in[0];
    const float* fix = (const float*)d_in[1];
    const int ITERS = 10;

    float* ws     = (float*)d_ws;
    float* gfix   = ws;                       // 3N
    float* vfA    = ws + (size_t)3*NVOX;      // 3N
    float* warped = ws + (size_t)6*NVOX;      // N
    bool big = ws_size >= (size_t)10*NVOX*sizeof(float);
    float* vfB = big ? (ws + (size_t)7*NVOX) : (float*)d_out;

    const int nb4 = (N4 + 255)/256;   // 800 blocks

    grad_kernel<<<nb4, 256, 0, stream>>>(fix, gfix);
    hipMemsetAsync(vfA, 0, (size_t)3*NVOX*sizeof(float), stream);

    dim3 sg(W_/32, H_/32, (D_/SCHUNK)*3);
    dim3 sb(8, 32);

    float* cur = vfA;
    float* alt = vfB;
    for (int it = 0; it < ITERS; ++it) {
        warp_kernel <<<nb4, 256, 0, stream>>>(mov, cur, warped);
        force_kernel<<<nb4, 256, 0, stream>>>(warped, fix, gfix, cur);
        float* sdst = (big && it == ITERS-1) ? (float*)d_out : alt;
        smooth3d_kernel<<<sg, sb, 0, stream>>>(cur, sdst);
        float* t = cur; cur = alt; alt = t;
    }
    if (!big) {
        // after even #iters the result sits in vfA
        hipMemcpyAsync(d_out, vfA, (size_t)3*NVOX*sizeof(float), hipMemcpyDeviceToDevice, stream);
    }
}